// Round 3
// baseline (8304.670 us; speedup 1.0000x reference)
//
#include <hip/hip_runtime.h>
#include <cstdint>
#include <cstddef>

namespace {

constexpr int kD    = 768;
constexpr int kDI   = 1536;
constexpr int kN    = 16;
constexpr int kDTR  = 48;
constexpr int kL    = 196;
constexpr int kKeep = 49;
constexpr int kB    = 8;
constexpr int kTok  = kB * kKeep;   // 392
constexpr int kPatchRows = kB * kL; // 1568
constexpr float kEps = 1e-5f;

// ---------------- block reduction (256 threads = 4 waves) ----------------
__device__ __forceinline__ float block_sum256(float x, float* sbuf) {
#pragma unroll
  for (int o = 32; o > 0; o >>= 1) x += __shfl_down(x, o, 64);
  int wid = threadIdx.x >> 6;
  if ((threadIdx.x & 63) == 0) sbuf[wid] = x;
  __syncthreads();
  float r = sbuf[0] + sbuf[1] + sbuf[2] + sbuf[3];
  __syncthreads();
  return r;
}

// ---------------- im2col for patch embedding ----------------
// A2[(b*196+l), (c*256+py*16+px)] = imgs[b,c,gy*16+py,gx*16+px]
__global__ __launch_bounds__(256) void im2col_kernel(const float* __restrict__ imgs,
                                                     float* __restrict__ A2) {
  int idx = blockIdx.x * 256 + threadIdx.x;
  if (idx >= kPatchRows * kD) return;
  int col = idx % kD;
  int row = idx / kD;
  int b = row / kL, l = row % kL;
  int gy = l / 14, gx = l % 14;
  int c   = col >> 8;
  int rem = col & 255;
  int py = rem >> 4, px = rem & 15;
  A2[idx] = imgs[((b * 3 + c) * 224 + gy * 16 + py) * 224 + gx * 16 + px];
}

// ---------------- generic GEMM: C[M,N] = act(A[M,lda] @ W[N,K]^T + bias) ----------------
// ACT: 0 = none, 1 = softplus
template <int ACT>
__global__ __launch_bounds__(256) void gemm_bt(const float* __restrict__ A, int lda,
                                               const float* __restrict__ W,
                                               const float* __restrict__ bias,
                                               float* __restrict__ C, int ldc,
                                               int M, int N, int K) {
  __shared__ float As[16][65];
  __shared__ float Ws[16][65];
  const int bm = blockIdx.x * 64;
  const int bn = blockIdx.y * 64;
  const int tid = threadIdx.x;
  const int tx = tid & 15;
  const int ty = tid >> 4;
  const int lk = tid & 15;   // k within tile
  const int lr = tid >> 4;   // row group
  float acc[4][4] = {};
  for (int kb = 0; kb < K; kb += 16) {
#pragma unroll
    for (int i = 0; i < 4; ++i) {
      int rowa = lr + i * 16;
      int gm = bm + rowa;
      As[lk][rowa] = (gm < M) ? A[(size_t)gm * lda + kb + lk] : 0.f;
      int gn = bn + rowa;
      Ws[lk][rowa] = (gn < N) ? W[(size_t)gn * K + kb + lk] : 0.f;
    }
    __syncthreads();
#pragma unroll
    for (int kk = 0; kk < 16; ++kk) {
      float a[4], w[4];
#pragma unroll
      for (int i = 0; i < 4; ++i) a[i] = As[kk][ty * 4 + i];
#pragma unroll
      for (int j = 0; j < 4; ++j) w[j] = Ws[kk][tx * 4 + j];
#pragma unroll
      for (int i = 0; i < 4; ++i)
#pragma unroll
        for (int j = 0; j < 4; ++j) acc[i][j] += a[i] * w[j];
    }
    __syncthreads();
  }
#pragma unroll
  for (int i = 0; i < 4; ++i) {
    int gm = bm + ty * 4 + i;
    if (gm >= M) continue;
#pragma unroll
    for (int j = 0; j < 4; ++j) {
      int gn = bn + tx * 4 + j;
      if (gn >= N) continue;
      float v = acc[i][j];
      if (bias) v += bias[gn];
      if (ACT == 1) v = (v > 20.f) ? v : log1pf(expf(v));
      C[(size_t)gm * ldc + gn] = v;
    }
  }
}

// ---------------- argsort / mask ----------------
// rank of element t = #{j : noise[j] < noise[t] or (== and j < t)}  (stable)
__global__ __launch_bounds__(256) void sort_kernel(const float* __restrict__ noise,
                                                   int* __restrict__ ids_keep,
                                                   float* __restrict__ mask_out,
                                                   float* __restrict__ idsr_out) {
  __shared__ float nb[kL];
  int b = blockIdx.x;
  int t = threadIdx.x;
  if (t < kL) nb[t] = noise[b * kL + t];
  __syncthreads();
  if (t < kL) {
    float v = nb[t];
    int rank = 0;
    for (int j = 0; j < kL; ++j) {
      float u = nb[j];
      rank += (u < v || (u == v && j < t)) ? 1 : 0;
    }
    if (rank < kKeep) ids_keep[b * kKeep + rank] = t;
    idsr_out[b * kL + t] = (float)rank;
    mask_out[b * kL + t] = (rank < kKeep) ? 0.f : 1.f;
  }
}

// ---------------- gather kept tokens (+ pos embed) ----------------
__global__ __launch_bounds__(256) void gather_kernel(const float* __restrict__ x0,
                                                     const int* __restrict__ ids_keep,
                                                     const float* __restrict__ pos,
                                                     float* __restrict__ hs) {
  int m = blockIdx.x;           // 0..391
  int b = m / kKeep, k = m % kKeep;
  int l = ids_keep[b * kKeep + k];
  const float* src = x0 + (size_t)(b * kL + l) * kD;
  const float* pp  = pos + (size_t)l * kD;
  float* dst = hs + (size_t)m * kD;
  for (int d = threadIdx.x; d < kD; d += 256) dst[d] = src[d] + pp[d];
}

// ---------------- res += hs ; out = LN(res)*w + b ----------------
template <int DD>
__global__ __launch_bounds__(256) void add_ln_kernel(const float* __restrict__ hs,
                                                     float* __restrict__ res,
                                                     const float* __restrict__ w,
                                                     const float* __restrict__ b,
                                                     float* __restrict__ out) {
  constexpr int PT = DD / 256;
  __shared__ float sbuf[4];
  int m = blockIdx.x;
  int t = threadIdx.x;
  float v[PT];
  float s = 0.f;
#pragma unroll
  for (int i = 0; i < PT; ++i) {
    int d = t + i * 256;
    v[i] = res[(size_t)m * DD + d] + hs[(size_t)m * DD + d];
    s += v[i];
  }
  float mean = block_sum256(s, sbuf) * (1.f / DD);
  float s2 = 0.f;
#pragma unroll
  for (int i = 0; i < PT; ++i) { float d0 = v[i] - mean; s2 += d0 * d0; }
  float var = block_sum256(s2, sbuf) * (1.f / DD);
  float rstd = rsqrtf(var + kEps);
#pragma unroll
  for (int i = 0; i < PT; ++i) {
    int d = t + i * 256;
    res[(size_t)m * DD + d] = v[i];
    out[(size_t)m * DD + d] = (v[i] - mean) * rstd * w[d] + b[d];
  }
}

// ---------------- depthwise causal conv (k=4) + SiLU ----------------
__global__ __launch_bounds__(256) void conv_silu_kernel(const float* __restrict__ xz,
                                                        const float* __restrict__ cw,
                                                        const float* __restrict__ cb,
                                                        float* __restrict__ xc) {
  int idx = blockIdx.x * 256 + threadIdx.x;
  if (idx >= kTok * kDI) return;
  int d  = idx % kDI;
  int mt = idx / kDI;
  int t = mt % kKeep;
  int b = mt / kKeep;
  float acc = cb[d];
#pragma unroll
  for (int k = 0; k < 4; ++k) {
    int tt = t - 3 + k;
    if (tt >= 0) acc += xz[(size_t)(b * kKeep + tt) * 3072 + d] * cw[d * 4 + k];
  }
  xc[idx] = acc / (1.f + expf(-acc));
}

// ---------------- selective scan ----------------
__global__ __launch_bounds__(256) void scan_kernel(const float* __restrict__ dt,
                                                   const float* __restrict__ xc,
                                                   const float* __restrict__ xdbl,
                                                   const float* __restrict__ A_log,
                                                   const float* __restrict__ D_skip,
                                                   float* __restrict__ y) {
  int d = blockIdx.x * 256 + threadIdx.x;  // 0..1535
  int b = blockIdx.y;
  float Aloc[kN];
#pragma unroll
  for (int n = 0; n < kN; ++n) Aloc[n] = -expf(A_log[d * kN + n]);
  float dsk = D_skip[d];
  float s[kN];
#pragma unroll
  for (int n = 0; n < kN; ++n) s[n] = 0.f;
  for (int t = 0; t < kKeep; ++t) {
    size_t row = (size_t)(b * kKeep + t);
    float dtv = dt[row * kDI + d];
    float xcv = xc[row * kDI + d];
    float dx = dtv * xcv;
    const float* bc = xdbl + row * 80 + kDTR;  // B at [48..63], C at [64..79]
    float yv = 0.f;
#pragma unroll
    for (int n = 0; n < kN; ++n) {
      float sn = expf(dtv * Aloc[n]) * s[n] + dx * bc[n];
      s[n] = sn;
      yv += sn * bc[kN + n];
    }
    y[row * kDI + d] = yv + dsk * xcv;
  }
}

// ---------------- y2 = (LN(y)*w+b) * silu(z) ----------------
__global__ __launch_bounds__(256) void ssm_ln_silu_kernel(const float* __restrict__ y,
                                                          const float* __restrict__ xz,
                                                          const float* __restrict__ w,
                                                          const float* __restrict__ b,
                                                          float* __restrict__ y2) {
  constexpr int PT = kDI / 256;  // 6
  __shared__ float sbuf[4];
  int m = blockIdx.x;
  int t = threadIdx.x;
  float v[PT];
  float s = 0.f;
#pragma unroll
  for (int i = 0; i < PT; ++i) {
    int d = t + i * 256;
    v[i] = y[(size_t)m * kDI + d];
    s += v[i];
  }
  float mean = block_sum256(s, sbuf) * (1.f / kDI);
  float s2 = 0.f;
#pragma unroll
  for (int i = 0; i < PT; ++i) { float d0 = v[i] - mean; s2 += d0 * d0; }
  float var = block_sum256(s2, sbuf) * (1.f / kDI);
  float rstd = rsqrtf(var + kEps);
#pragma unroll
  for (int i = 0; i < PT; ++i) {
    int d = t + i * 256;
    float z = xz[(size_t)m * 3072 + kDI + d];
    y2[(size_t)m * kDI + d] =
        ((v[i] - mean) * rstd * w[d] + b[d]) * (z / (1.f + expf(-z)));
  }
}

}  // namespace

extern "C" void kernel_launch(void* const* d_in, const int* in_sizes, int n_in,
                              void* d_out, int out_size, void* d_ws, size_t ws_size,
                              hipStream_t stream) {
  const float* imgs       = (const float*)d_in[0];
  const float* noise      = (const float*)d_in[1];
  const float* patch_w    = (const float*)d_in[2];
  const float* patch_b    = (const float*)d_in[3];
  const float* pos_embed  = (const float*)d_in[4];
  const float* ln_w       = (const float*)d_in[5];
  const float* ln_b       = (const float*)d_in[6];
  const float* in_proj_w  = (const float*)d_in[7];
  const float* conv_w     = (const float*)d_in[8];
  const float* conv_b     = (const float*)d_in[9];
  const float* x_proj_w   = (const float*)d_in[10];
  const float* dt_w       = (const float*)d_in[11];
  const float* dt_b       = (const float*)d_in[12];
  const float* A_log      = (const float*)d_in[13];
  const float* D_skip     = (const float*)d_in[14];
  const float* ssm_ln_w   = (const float*)d_in[15];
  const float* ssm_ln_b   = (const float*)d_in[16];
  const float* out_proj_w = (const float*)d_in[17];
  const float* final_ln_w = (const float*)d_in[18];
  const float* final_ln_b = (const float*)d_in[19];

  float* out      = (float*)d_out;
  float* latent   = out;                       // 392*768 = 301056
  float* mask_out = out + 301056;              // 8*196  = 1568
  float* idsr_out = out + 301056 + 1568;       // 8*196  = 1568

  // workspace layout (floats)
  float* ws   = (float*)d_ws;
  float* hs   = ws;                 // 301056
  float* res  = hs   + 301056;      // 301056
  float* h    = res  + 301056;      // 301056
  float* xz   = h    + 301056;      // 1204224 (392x3072)
  float* xc   = xz   + 1204224;     // 602112  (392x1536)
  float* xdbl = xc   + 602112;      // 31360   (392x80)
  float* dtb_ = xdbl + 31360;       // 602112  (392x1536)
  float* ybuf = dtb_ + 602112;      // 602112
  float* y2   = ybuf + 602112;      // 602112
  int*   ids_keep = (int*)(y2 + 602112);  // 392 ints
  // patch-stage aliases (disjoint in time with layer buffers)
  float* A2 = xz;  // 1568x768 = 1204224 fits in xz exactly
  float* x0 = xc;  // 1568x768 fits in xc+xdbl+dtb_ (1235584 >= 1204224)

  // ---- patch embedding: im2col + GEMM (bias = patch_b) ----
  {
    int tot = kPatchRows * kD;
    im2col_kernel<<<(tot + 255) / 256, 256, 0, stream>>>(imgs, A2);
    dim3 g((kPatchRows + 63) / 64, (kD + 63) / 64);
    gemm_bt<0><<<g, 256, 0, stream>>>(A2, kD, patch_w, patch_b, x0, kD,
                                      kPatchRows, kD, kD);
  }

  // ---- masking (argsort ranks) ----
  sort_kernel<<<kB, 256, 0, stream>>>(noise, ids_keep, mask_out, idsr_out);

  // ---- gather kept tokens + pos embed ----
  gather_kernel<<<kTok, 256, 0, stream>>>(x0, ids_keep, pos_embed, hs);

  // ---- res = 0 ----
  hipMemsetAsync(res, 0, (size_t)kTok * kD * sizeof(float), stream);

  // ---- 12 Mamba blocks ----
  for (int l = 0; l < 12; ++l) {
    const float* lnw  = ln_w  + (size_t)l * kD;
    const float* lnb  = ln_b  + (size_t)l * kD;
    const float* ipw  = in_proj_w  + (size_t)l * 2 * kDI * kD;
    const float* cw   = conv_w     + (size_t)l * kDI * 4;
    const float* cb   = conv_b     + (size_t)l * kDI;
    const float* xpw  = x_proj_w   + (size_t)l * (kDTR + 2 * kN) * kDI;
    const float* dtw  = dt_w       + (size_t)l * kDI * kDTR;
    const float* dtbv = dt_b       + (size_t)l * kDI;
    const float* alog = A_log      + (size_t)l * kDI * kN;
    const float* dsk  = D_skip     + (size_t)l * kDI;
    const float* slw  = ssm_ln_w   + (size_t)l * kDI;
    const float* slb  = ssm_ln_b   + (size_t)l * kDI;
    const float* opw  = out_proj_w + (size_t)l * kD * kDI;

    // res += hs ; h = LN(res)
    add_ln_kernel<kD><<<kTok, 256, 0, stream>>>(hs, res, lnw, lnb, h);

    // xz = h @ ipw^T   (392 x 3072)
    gemm_bt<0><<<dim3(7, 48), 256, 0, stream>>>(h, kD, ipw, nullptr, xz, 2 * kDI,
                                                kTok, 2 * kDI, kD);

    // xc = silu(causal depthwise conv(xi) + cb)
    conv_silu_kernel<<<(kTok * kDI + 255) / 256, 256, 0, stream>>>(xz, cw, cb, xc);

    // xdbl = xc @ xpw^T  (392 x 80)
    gemm_bt<0><<<dim3(7, 2), 256, 0, stream>>>(xc, kDI, xpw, nullptr, xdbl, 80,
                                               kTok, 80, kDI);

    // dt = softplus(dtr @ dtw^T + dt_b)  (392 x 1536), dtr = xdbl[:, :48]
    gemm_bt<1><<<dim3(7, 24), 256, 0, stream>>>(xdbl, 80, dtw, dtbv, dtb_, kDI,
                                                kTok, kDI, kDTR);

    // selective scan -> ybuf (+ D skip)
    scan_kernel<<<dim3(6, kB), 256, 0, stream>>>(dtb_, xc, xdbl, alog, dsk, ybuf);

    // y2 = LN(ybuf)*slw+slb * silu(z)
    ssm_ln_silu_kernel<<<kTok, 256, 0, stream>>>(ybuf, xz, slw, slb, y2);

    // hs = y2 @ opw^T  (392 x 768)
    gemm_bt<0><<<dim3(7, 12), 256, 0, stream>>>(y2, kDI, opw, nullptr, hs, kD,
                                                kTok, kD, kDI);
  }

  // ---- latent = LN(res + hs) ----
  add_ln_kernel<kD><<<kTok, 256, 0, stream>>>(hs, res, final_ln_w, final_ln_b,
                                              latent);
}

// Round 7
// 4542.214 us; speedup vs baseline: 1.8283x; 1.8283x over previous
//
#include <hip/hip_runtime.h>
#include <cstdint>
#include <cstddef>

namespace {

constexpr int kD    = 768;
constexpr int kDI   = 1536;
constexpr int kN    = 16;
constexpr int kDTR  = 48;
constexpr int kL    = 196;
constexpr int kKeep = 49;
constexpr int kB    = 8;
constexpr int kTok  = kB * kKeep;   // 392
constexpr int kPatchRows = kB * kL; // 1568
constexpr float kEps = 1e-5f;

// ---------------- block reduction (256 threads = 4 waves) ----------------
__device__ __forceinline__ float block_sum256(float x, float* sbuf) {
#pragma unroll
  for (int o = 32; o > 0; o >>= 1) x += __shfl_down(x, o, 64);
  int wid = threadIdx.x >> 6;
  if ((threadIdx.x & 63) == 0) sbuf[wid] = x;
  __syncthreads();
  float r = sbuf[0] + sbuf[1] + sbuf[2] + sbuf[3];
  __syncthreads();
  return r;
}

// ---------------- im2col for patch embedding ----------------
__global__ __launch_bounds__(256) void im2col_kernel(const float* __restrict__ imgs,
                                                     float* __restrict__ A2) {
  int idx = blockIdx.x * 256 + threadIdx.x;
  if (idx >= kPatchRows * kD) return;
  int col = idx % kD;
  int row = idx / kD;
  int b = row / kL, l = row % kL;
  int gy = l / 14, gx = l % 14;
  int c   = col >> 8;
  int rem = col & 255;
  int py = rem >> 4, px = rem & 15;
  A2[idx] = imgs[((b * 3 + c) * 224 + gy * 16 + py) * 224 + gx * 16 + px];
}

// ---------------- GEMM: C[M,N] (+)= act(A[M,lda] @ W[N,K]^T + bias) ----------------
// 64x64 tile, 256 threads, 4x4 micro, double-buffered LDS, float4 staging.
// SPLIT>1: blockIdx.z selects K-chunk; accumulate into C via HW f32 atomics
// (C must be zeroed first; bias added by z==0; ACT must be 0).
// SPLIT==1: plain float4 store, optional ACT (1 = softplus).
template <int ACT, int SPLIT>
__global__ __launch_bounds__(256) void gemm_bt(const float* __restrict__ A, int lda,
                                               const float* __restrict__ W,
                                               const float* __restrict__ bias,
                                               float* __restrict__ C, int ldc,
                                               int M, int N, int K) {
  __shared__ float As[2][16][68];  // [buf][k][row], +4 pad keeps b128 16B-aligned
  __shared__ float Ws[2][16][68];
  const int bm = blockIdx.x * 64;
  const int bn = blockIdx.y * 64;
  const int kc = K / SPLIT;
  const int k0 = blockIdx.z * kc;
  const int nk = kc / 16;
  const int tid = threadIdx.x;
  const int tx = tid & 15;
  const int ty = tid >> 4;
  const int sr = tid >> 2;        // staged row 0..63
  const int sk = (tid & 3) * 4;   // staged k offset 0/4/8/12
  const bool mok = (bm + sr) < M;
  const float* Ap = A + (size_t)(bm + sr) * lda + k0 + sk;
  const float* Wp = W + (size_t)(bn + sr) * K + k0 + sk;

  float4 a4 = mok ? *(const float4*)Ap : make_float4(0.f, 0.f, 0.f, 0.f);
  float4 w4 = *(const float4*)Wp;

  float acc[4][4] = {};
  int buf = 0;
  As[0][sk + 0][sr] = a4.x; As[0][sk + 1][sr] = a4.y;
  As[0][sk + 2][sr] = a4.z; As[0][sk + 3][sr] = a4.w;
  Ws[0][sk + 0][sr] = w4.x; Ws[0][sk + 1][sr] = w4.y;
  Ws[0][sk + 2][sr] = w4.z; Ws[0][sk + 3][sr] = w4.w;
  __syncthreads();

  for (int t = 1; t < nk; ++t) {
    float4 a4n = mok ? *(const float4*)(Ap + t * 16) : make_float4(0.f, 0.f, 0.f, 0.f);
    float4 w4n = *(const float4*)(Wp + t * 16);
#pragma unroll
    for (int kk = 0; kk < 16; ++kk) {
      float4 av = *(const float4*)&As[buf][kk][ty * 4];
      float4 wv = *(const float4*)&Ws[buf][kk][tx * 4];
      float af[4] = {av.x, av.y, av.z, av.w};
      float wf[4] = {wv.x, wv.y, wv.z, wv.w};
#pragma unroll
      for (int i = 0; i < 4; ++i)
#pragma unroll
        for (int j = 0; j < 4; ++j) acc[i][j] += af[i] * wf[j];
    }
    __syncthreads();
    As[buf ^ 1][sk + 0][sr] = a4n.x; As[buf ^ 1][sk + 1][sr] = a4n.y;
    As[buf ^ 1][sk + 2][sr] = a4n.z; As[buf ^ 1][sk + 3][sr] = a4n.w;
    Ws[buf ^ 1][sk + 0][sr] = w4n.x; Ws[buf ^ 1][sk + 1][sr] = w4n.y;
    Ws[buf ^ 1][sk + 2][sr] = w4n.z; Ws[buf ^ 1][sk + 3][sr] = w4n.w;
    __syncthreads();
    buf ^= 1;
  }
#pragma unroll
  for (int kk = 0; kk < 16; ++kk) {
    float4 av = *(const float4*)&As[buf][kk][ty * 4];
    float4 wv = *(const float4*)&Ws[buf][kk][tx * 4];
    float af[4] = {av.x, av.y, av.z, av.w};
    float wf[4] = {wv.x, wv.y, wv.z, wv.w};
#pragma unroll
    for (int i = 0; i < 4; ++i)
#pragma unroll
      for (int j = 0; j < 4; ++j) acc[i][j] += af[i] * wf[j];
  }

  const int gn0 = bn + tx * 4;
#pragma unroll
  for (int i = 0; i < 4; ++i) {
    int gm = bm + ty * 4 + i;
    if (gm >= M) continue;
    if (SPLIT == 1) {
      float4 v;
      v.x = acc[i][0]; v.y = acc[i][1]; v.z = acc[i][2]; v.w = acc[i][3];
      if (bias) {
        v.x += bias[gn0 + 0]; v.y += bias[gn0 + 1];
        v.z += bias[gn0 + 2]; v.w += bias[gn0 + 3];
      }
      if (ACT == 1) {
        v.x = (v.x > 20.f) ? v.x : log1pf(expf(v.x));
        v.y = (v.y > 20.f) ? v.y : log1pf(expf(v.y));
        v.z = (v.z > 20.f) ? v.z : log1pf(expf(v.z));
        v.w = (v.w > 20.f) ? v.w : log1pf(expf(v.w));
      }
      *(float4*)&C[(size_t)gm * ldc + gn0] = v;
    } else {
#pragma unroll
      for (int j = 0; j < 4; ++j) {
        float v = acc[i][j];
        if (bias && blockIdx.z == 0) v += bias[gn0 + j];
        __hip_atomic_fetch_add(&C[(size_t)gm * ldc + gn0 + j], v,
                               __ATOMIC_RELAXED, __HIP_MEMORY_SCOPE_AGENT);
      }
    }
  }
}

// ---------------- argsort / mask ----------------
__global__ __launch_bounds__(256) void sort_kernel(const float* __restrict__ noise,
                                                   int* __restrict__ ids_keep,
                                                   float* __restrict__ mask_out,
                                                   float* __restrict__ idsr_out) {
  __shared__ float nb[kL];
  int b = blockIdx.x;
  int t = threadIdx.x;
  if (t < kL) nb[t] = noise[b * kL + t];
  __syncthreads();
  if (t < kL) {
    float v = nb[t];
    int rank = 0;
    for (int j = 0; j < kL; ++j) {
      float u = nb[j];
      rank += (u < v || (u == v && j < t)) ? 1 : 0;
    }
    if (rank < kKeep) ids_keep[b * kKeep + rank] = t;
    idsr_out[b * kL + t] = (float)rank;
    mask_out[b * kL + t] = (rank < kKeep) ? 0.f : 1.f;
  }
}

// ---------------- gather kept tokens (+ pos embed) ----------------
__global__ __launch_bounds__(256) void gather_kernel(const float* __restrict__ x0,
                                                     const int* __restrict__ ids_keep,
                                                     const float* __restrict__ pos,
                                                     float* __restrict__ hs) {
  int m = blockIdx.x;
  int b = m / kKeep, k = m % kKeep;
  int l = ids_keep[b * kKeep + k];
  const float* src = x0 + (size_t)(b * kL + l) * kD;
  const float* pp  = pos + (size_t)l * kD;
  float* dst = hs + (size_t)m * kD;
  for (int d = threadIdx.x; d < kD; d += 256) dst[d] = src[d] + pp[d];
}

// ---------------- res += hs ; out = LN(res)*w + b ----------------
template <int DD>
__global__ __launch_bounds__(256) void add_ln_kernel(const float* __restrict__ hs,
                                                     float* __restrict__ res,
                                                     const float* __restrict__ w,
                                                     const float* __restrict__ b,
                                                     float* __restrict__ out) {
  constexpr int PT = DD / 256;
  __shared__ float sbuf[4];
  int m = blockIdx.x;
  int t = threadIdx.x;
  float v[PT];
  float s = 0.f;
#pragma unroll
  for (int i = 0; i < PT; ++i) {
    int d = t + i * 256;
    v[i] = res[(size_t)m * DD + d] + hs[(size_t)m * DD + d];
    s += v[i];
  }
  float mean = block_sum256(s, sbuf) * (1.f / DD);
  float s2 = 0.f;
#pragma unroll
  for (int i = 0; i < PT; ++i) { float d0 = v[i] - mean; s2 += d0 * d0; }
  float var = block_sum256(s2, sbuf) * (1.f / DD);
  float rstd = rsqrtf(var + kEps);
#pragma unroll
  for (int i = 0; i < PT; ++i) {
    int d = t + i * 256;
    res[(size_t)m * DD + d] = v[i];
    out[(size_t)m * DD + d] = (v[i] - mean) * rstd * w[d] + b[d];
  }
}

// ---------------- depthwise causal conv (k=4) + SiLU ----------------
__global__ __launch_bounds__(256) void conv_silu_kernel(const float* __restrict__ xz,
                                                        const float* __restrict__ cw,
                                                        const float* __restrict__ cb,
                                                        float* __restrict__ xc) {
  int idx = blockIdx.x * 256 + threadIdx.x;
  if (idx >= kTok * kDI) return;
  int d  = idx % kDI;
  int mt = idx / kDI;
  int t = mt % kKeep;
  int b = mt / kKeep;
  float acc = cb[d];
#pragma unroll
  for (int k = 0; k < 4; ++k) {
    int tt = t - 3 + k;
    if (tt >= 0) acc += xz[(size_t)(b * kKeep + tt) * 3072 + d] * cw[d * 4 + k];
  }
  xc[idx] = acc / (1.f + expf(-acc));
}

// ---------------- xdbl = xc @ xpw^T  (392 x 80, K=1536) ----------------
// one block per token row; xc row staged in LDS; each wave handles 20 outputs
__global__ __launch_bounds__(256) void xdbl_kernel(const float* __restrict__ xc,
                                                   const float* __restrict__ xpw,
                                                   float* __restrict__ xdbl) {
  __shared__ float row[kDI];
  int m = blockIdx.x;
  for (int i = threadIdx.x; i < kDI / 4; i += 256)
    *(float4*)&row[i * 4] = *(const float4*)&xc[(size_t)m * kDI + i * 4];
  __syncthreads();
  int w = threadIdx.x >> 6;
  int lane = threadIdx.x & 63;
  for (int q = 0; q < 20; ++q) {
    int n = w * 20 + q;
    const float* wr = xpw + (size_t)n * kDI;
    float s = 0.f;
    for (int k = lane; k < kDI; k += 64) s += row[k] * wr[k];
#pragma unroll
    for (int o = 32; o > 0; o >>= 1) s += __shfl_down(s, o, 64);
    if (lane == 0) xdbl[(size_t)m * 80 + n] = s;
  }
}

// ---------------- selective scan (64-thread blocks, B/C in LDS) ----------------
__global__ __launch_bounds__(64) void scan_kernel(const float* __restrict__ dt,
                                                  const float* __restrict__ xc,
                                                  const float* __restrict__ xdbl,
                                                  const float* __restrict__ A_log,
                                                  const float* __restrict__ D_skip,
                                                  float* __restrict__ y) {
  __shared__ float bcs[kKeep][32];
  int d = blockIdx.x * 64 + threadIdx.x;  // grid.x = 24
  int b = blockIdx.y;
  for (int i = threadIdx.x; i < kKeep * 32; i += 64) {
    int t = i >> 5, n = i & 31;
    bcs[t][n] = xdbl[(size_t)(b * kKeep + t) * 80 + kDTR + n];
  }
  __syncthreads();
  float Aloc[kN];
#pragma unroll
  for (int n = 0; n < kN; ++n) Aloc[n] = -expf(A_log[d * kN + n]);
  float dsk = D_skip[d];
  float s[kN];
#pragma unroll
  for (int n = 0; n < kN; ++n) s[n] = 0.f;

  size_t base = (size_t)(b * kKeep) * kDI + d;
  float dtv = dt[base];
  float xcv = xc[base];
  for (int t = 0; t < kKeep; ++t) {
    float dtn = 0.f, xcn = 0.f;
    if (t + 1 < kKeep) {                 // prefetch next step
      dtn = dt[base + (size_t)(t + 1) * kDI];
      xcn = xc[base + (size_t)(t + 1) * kDI];
    }
    float dx = dtv * xcv;
    float yv = 0.f;
#pragma unroll
    for (int n = 0; n < kN; ++n) {
      float sn = expf(dtv * Aloc[n]) * s[n] + dx * bcs[t][n];
      s[n] = sn;
      yv += sn * bcs[t][16 + n];
    }
    y[base + (size_t)t * kDI] = yv + dsk * xcv;
    dtv = dtn; xcv = xcn;
  }
}

// ---------------- y2 = (LN(y)*w+b) * silu(z) ----------------
__global__ __launch_bounds__(256) void ssm_ln_silu_kernel(const float* __restrict__ y,
                                                          const float* __restrict__ xz,
                                                          const float* __restrict__ w,
                                                          const float* __restrict__ b,
                                                          float* __restrict__ y2) {
  constexpr int PT = kDI / 256;  // 6
  __shared__ float sbuf[4];
  int m = blockIdx.x;
  int t = threadIdx.x;
  float v[PT];
  float s = 0.f;
#pragma unroll
  for (int i = 0; i < PT; ++i) {
    int d = t + i * 256;
    v[i] = y[(size_t)m * kDI + d];
    s += v[i];
  }
  float mean = block_sum256(s, sbuf) * (1.f / kDI);
  float s2 = 0.f;
#pragma unroll
  for (int i = 0; i < PT; ++i) { float d0 = v[i] - mean; s2 += d0 * d0; }
  float var = block_sum256(s2, sbuf) * (1.f / kDI);
  float rstd = rsqrtf(var + kEps);
#pragma unroll
  for (int i = 0; i < PT; ++i) {
    int d = t + i * 256;
    float z = xz[(size_t)m * 3072 + kDI + d];
    y2[(size_t)m * kDI + d] =
        ((v[i] - mean) * rstd * w[d] + b[d]) * (z / (1.f + expf(-z)));
  }
}

}  // namespace

extern "C" void kernel_launch(void* const* d_in, const int* in_sizes, int n_in,
                              void* d_out, int out_size, void* d_ws, size_t ws_size,
                              hipStream_t stream) {
  const float* imgs       = (const float*)d_in[0];
  const float* noise      = (const float*)d_in[1];
  const float* patch_w    = (const float*)d_in[2];
  const float* patch_b    = (const float*)d_in[3];
  const float* pos_embed  = (const float*)d_in[4];
  const float* ln_w       = (const float*)d_in[5];
  const float* ln_b       = (const float*)d_in[6];
  const float* in_proj_w  = (const float*)d_in[7];
  const float* conv_w     = (const float*)d_in[8];
  const float* conv_b     = (const float*)d_in[9];
  const float* x_proj_w   = (const float*)d_in[10];
  const float* dt_w       = (const float*)d_in[11];
  const float* dt_b       = (const float*)d_in[12];
  const float* A_log      = (const float*)d_in[13];
  const float* D_skip     = (const float*)d_in[14];
  const float* ssm_ln_w   = (const float*)d_in[15];
  const float* ssm_ln_b   = (const float*)d_in[16];
  const float* out_proj_w = (const float*)d_in[17];
  const float* final_ln_w = (const float*)d_in[18];
  const float* final_ln_b = (const float*)d_in[19];

  float* out      = (float*)d_out;
  float* latent   = out;                       // 392*768
  float* mask_out = out + 301056;              // 8*196
  float* idsr_out = out + 301056 + 1568;       // 8*196

  // workspace layout (floats)
  float* ws   = (float*)d_ws;
  float* hs   = ws;                 // 301056
  float* res  = hs   + 301056;      // 301056
  float* h    = res  + 301056;      // 301056
  float* xz   = h    + 301056;      // 1204224 (392x3072)
  float* xc   = xz   + 1204224;     // 602112  (392x1536)
  float* xdbl = xc   + 602112;      // 31360   (392x80)
  float* dtb_ = xdbl + 31360;       // 602112  (392x1536)
  float* ybuf = dtb_ + 602112;      // 602112
  float* y2   = ybuf + 602112;      // 602112
  int*   ids_keep = (int*)(y2 + 602112);  // 392 ints
  // patch-stage aliases (disjoint in time with layer buffers)
  float* A2 = xz;  // 1568x768 fits in xz exactly
  float* x0 = xc;  // 1568x768 fits in xc+xdbl+dtb_

  // ---- patch embedding: im2col + split-K GEMM (bias = patch_b) ----
  {
    int tot = kPatchRows * kD;
    im2col_kernel<<<(tot + 255) / 256, 256, 0, stream>>>(imgs, A2);
    hipMemsetAsync(x0, 0, (size_t)kPatchRows * kD * sizeof(float), stream);
    gemm_bt<0, 4><<<dim3(25, 12, 4), 256, 0, stream>>>(A2, kD, patch_w, patch_b,
                                                       x0, kD, kPatchRows, kD, kD);
  }

  // ---- masking (argsort ranks) ----
  sort_kernel<<<kB, 256, 0, stream>>>(noise, ids_keep, mask_out, idsr_out);

  // ---- gather kept tokens + pos embed ----
  gather_kernel<<<kTok, 256, 0, stream>>>(x0, ids_keep, pos_embed, hs);

  // ---- res = 0 ----
  hipMemsetAsync(res, 0, (size_t)kTok * kD * sizeof(float), stream);

  // ---- 12 Mamba blocks ----
  for (int l = 0; l < 12; ++l) {
    const float* lnw  = ln_w  + (size_t)l * kD;
    const float* lnb  = ln_b  + (size_t)l * kD;
    const float* ipw  = in_proj_w  + (size_t)l * 2 * kDI * kD;
    const float* cw   = conv_w     + (size_t)l * kDI * 4;
    const float* cb   = conv_b     + (size_t)l * kDI;
    const float* xpw  = x_proj_w   + (size_t)l * (kDTR + 2 * kN) * kDI;
    const float* dtw  = dt_w       + (size_t)l * kDI * kDTR;
    const float* dtbv = dt_b       + (size_t)l * kDI;
    const float* alog = A_log      + (size_t)l * kDI * kN;
    const float* dsk  = D_skip     + (size_t)l * kDI;
    const float* slw  = ssm_ln_w   + (size_t)l * kDI;
    const float* slb  = ssm_ln_b   + (size_t)l * kDI;
    const float* opw  = out_proj_w + (size_t)l * kD * kDI;

    // res += hs ; h = LN(res)
    add_ln_kernel<kD><<<kTok, 256, 0, stream>>>(hs, res, lnw, lnb, h);

    // xz = h @ ipw^T   (392 x 3072, K=768), split-K x4 via atomics
    hipMemsetAsync(xz, 0, (size_t)kTok * 2 * kDI * sizeof(float), stream);
    gemm_bt<0, 4><<<dim3(7, 48, 4), 256, 0, stream>>>(h, kD, ipw, nullptr, xz,
                                                      2 * kDI, kTok, 2 * kDI, kD);

    // xc = silu(causal depthwise conv(xi) + cb)
    conv_silu_kernel<<<(kTok * kDI + 255) / 256, 256, 0, stream>>>(xz, cw, cb, xc);

    // xdbl = xc @ xpw^T  (392 x 80)
    xdbl_kernel<<<kTok, 256, 0, stream>>>(xc, xpw, xdbl);

    // dt = softplus(dtr @ dtw^T + dt_b)  (392 x 1536, K=48)
    gemm_bt<1, 1><<<dim3(7, 24, 1), 256, 0, stream>>>(xdbl, 80, dtw, dtbv, dtb_,
                                                      kDI, kTok, kDI, kDTR);

    // selective scan -> ybuf (+ D skip)
    scan_kernel<<<dim3(24, kB), 64, 0, stream>>>(dtb_, xc, xdbl, alog, dsk, ybuf);

    // y2 = LN(ybuf)*slw+slb * silu(z)
    ssm_ln_silu_kernel<<<kTok, 256, 0, stream>>>(ybuf, xz, slw, slb, y2);

    // hs = y2 @ opw^T  (392 x 768, K=1536), split-K x8 via atomics
    hipMemsetAsync(hs, 0, (size_t)kTok * kD * sizeof(float), stream);
    gemm_bt<0, 8><<<dim3(7, 12, 8), 256, 0, stream>>>(y2, kDI, opw, nullptr, hs,
                                                      kD, kTok, kD, kDI);
  }

  // ---- latent = LN(res + hs) ----
  add_ln_kernel<kD><<<kTok, 256, 0, stream>>>(hs, res, final_ln_w, final_ln_b,
                                              latent);
}

// Round 8
// 2658.926 us; speedup vs baseline: 3.1233x; 1.7083x over previous
//
#include <hip/hip_runtime.h>
#include <cstdint>
#include <cstddef>

namespace {

constexpr int kD    = 768;
constexpr int kDI   = 1536;
constexpr int kN    = 16;
constexpr int kDTR  = 48;
constexpr int kL    = 196;
constexpr int kKeep = 49;
constexpr int kB    = 8;
constexpr int kTok  = kB * kKeep;   // 392
constexpr int kPatchRows = kB * kL; // 1568
constexpr float kEps = 1e-5f;

// ---------------- block reduction (256 threads = 4 waves) ----------------
__device__ __forceinline__ float block_sum256(float x, float* sbuf) {
#pragma unroll
  for (int o = 32; o > 0; o >>= 1) x += __shfl_down(x, o, 64);
  int wid = threadIdx.x >> 6;
  if ((threadIdx.x & 63) == 0) sbuf[wid] = x;
  __syncthreads();
  float r = sbuf[0] + sbuf[1] + sbuf[2] + sbuf[3];
  __syncthreads();
  return r;
}

// ---------------- im2col for patch embedding ----------------
__global__ __launch_bounds__(256) void im2col_kernel(const float* __restrict__ imgs,
                                                     float* __restrict__ A2) {
  int idx = blockIdx.x * 256 + threadIdx.x;
  if (idx >= kPatchRows * kD) return;
  int col = idx % kD;
  int row = idx / kD;
  int b = row / kL, l = row % kL;
  int gy = l / 14, gx = l % 14;
  int c   = col >> 8;
  int rem = col & 255;
  int py = rem >> 4, px = rem & 15;
  A2[idx] = imgs[((b * 3 + c) * 224 + gy * 16 + py) * 224 + gx * 16 + px];
}

// ---------------- GEMM: C[M,N] (+)= act(A[M,lda] @ W[N,K]^T + bias) ----------------
// 64x64 tile, 256 threads, 4x4 micro, double-buffered LDS, float4 staging.
// Handles M and N overhang (N must be a multiple of 4).
// SPLIT>1: blockIdx.z selects K-chunk; accumulate into C via HW f32 atomics
// (C must be zeroed first; bias added by z==0; ACT must be 0).
// SPLIT==1: plain float4 store, optional ACT (1 = softplus).
template <int ACT, int SPLIT>
__global__ __launch_bounds__(256) void gemm_bt(const float* __restrict__ A, int lda,
                                               const float* __restrict__ W,
                                               const float* __restrict__ bias,
                                               float* __restrict__ C, int ldc,
                                               int M, int N, int K) {
  __shared__ float As[2][16][68];  // [buf][k][row], +4 pad keeps b128 16B-aligned
  __shared__ float Ws[2][16][68];
  const int bm = blockIdx.x * 64;
  const int bn = blockIdx.y * 64;
  const int kc = K / SPLIT;
  const int k0 = blockIdx.z * kc;
  const int nk = kc / 16;
  const int tid = threadIdx.x;
  const int tx = tid & 15;
  const int ty = tid >> 4;
  const int sr = tid >> 2;        // staged row 0..63
  const int sk = (tid & 3) * 4;   // staged k offset 0/4/8/12
  const bool mok = (bm + sr) < M;
  const bool nok = (bn + sr) < N;
  const float* Ap = A + (size_t)(bm + sr) * lda + k0 + sk;
  const float* Wp = W + (size_t)(bn + sr) * K + k0 + sk;

  float4 a4 = mok ? *(const float4*)Ap : make_float4(0.f, 0.f, 0.f, 0.f);
  float4 w4 = nok ? *(const float4*)Wp : make_float4(0.f, 0.f, 0.f, 0.f);

  float acc[4][4] = {};
  int buf = 0;
  As[0][sk + 0][sr] = a4.x; As[0][sk + 1][sr] = a4.y;
  As[0][sk + 2][sr] = a4.z; As[0][sk + 3][sr] = a4.w;
  Ws[0][sk + 0][sr] = w4.x; Ws[0][sk + 1][sr] = w4.y;
  Ws[0][sk + 2][sr] = w4.z; Ws[0][sk + 3][sr] = w4.w;
  __syncthreads();

  for (int t = 1; t < nk; ++t) {
    float4 a4n = mok ? *(const float4*)(Ap + t * 16) : make_float4(0.f, 0.f, 0.f, 0.f);
    float4 w4n = nok ? *(const float4*)(Wp + t * 16) : make_float4(0.f, 0.f, 0.f, 0.f);
#pragma unroll
    for (int kk = 0; kk < 16; ++kk) {
      float4 av = *(const float4*)&As[buf][kk][ty * 4];
      float4 wv = *(const float4*)&Ws[buf][kk][tx * 4];
      float af[4] = {av.x, av.y, av.z, av.w};
      float wf[4] = {wv.x, wv.y, wv.z, wv.w};
#pragma unroll
      for (int i = 0; i < 4; ++i)
#pragma unroll
        for (int j = 0; j < 4; ++j) acc[i][j] += af[i] * wf[j];
    }
    __syncthreads();
    As[buf ^ 1][sk + 0][sr] = a4n.x; As[buf ^ 1][sk + 1][sr] = a4n.y;
    As[buf ^ 1][sk + 2][sr] = a4n.z; As[buf ^ 1][sk + 3][sr] = a4n.w;
    Ws[buf ^ 1][sk + 0][sr] = w4n.x; Ws[buf ^ 1][sk + 1][sr] = w4n.y;
    Ws[buf ^ 1][sk + 2][sr] = w4n.z; Ws[buf ^ 1][sk + 3][sr] = w4n.w;
    __syncthreads();
    buf ^= 1;
  }
#pragma unroll
  for (int kk = 0; kk < 16; ++kk) {
    float4 av = *(const float4*)&As[buf][kk][ty * 4];
    float4 wv = *(const float4*)&Ws[buf][kk][tx * 4];
    float af[4] = {av.x, av.y, av.z, av.w};
    float wf[4] = {wv.x, wv.y, wv.z, wv.w};
#pragma unroll
    for (int i = 0; i < 4; ++i)
#pragma unroll
      for (int j = 0; j < 4; ++j) acc[i][j] += af[i] * wf[j];
  }

  const int gn0 = bn + tx * 4;
  if (gn0 >= N) return;  // N % 4 == 0 -> whole float4 in/out of bounds
#pragma unroll
  for (int i = 0; i < 4; ++i) {
    int gm = bm + ty * 4 + i;
    if (gm >= M) continue;
    if (SPLIT == 1) {
      float4 v;
      v.x = acc[i][0]; v.y = acc[i][1]; v.z = acc[i][2]; v.w = acc[i][3];
      if (bias) {
        v.x += bias[gn0 + 0]; v.y += bias[gn0 + 1];
        v.z += bias[gn0 + 2]; v.w += bias[gn0 + 3];
      }
      if (ACT == 1) {
        v.x = (v.x > 20.f) ? v.x : log1pf(expf(v.x));
        v.y = (v.y > 20.f) ? v.y : log1pf(expf(v.y));
        v.z = (v.z > 20.f) ? v.z : log1pf(expf(v.z));
        v.w = (v.w > 20.f) ? v.w : log1pf(expf(v.w));
      }
      *(float4*)&C[(size_t)gm * ldc + gn0] = v;
    } else {
#pragma unroll
      for (int j = 0; j < 4; ++j) {
        float v = acc[i][j];
        if (bias && blockIdx.z == 0) v += bias[gn0 + j];
        __hip_atomic_fetch_add(&C[(size_t)gm * ldc + gn0 + j], v,
                               __ATOMIC_RELAXED, __HIP_MEMORY_SCOPE_AGENT);
      }
    }
  }
}

// ---------------- argsort / mask ----------------
__global__ __launch_bounds__(256) void sort_kernel(const float* __restrict__ noise,
                                                   int* __restrict__ ids_keep,
                                                   float* __restrict__ mask_out,
                                                   float* __restrict__ idsr_out) {
  __shared__ float nb[kL];
  int b = blockIdx.x;
  int t = threadIdx.x;
  if (t < kL) nb[t] = noise[b * kL + t];
  __syncthreads();
  if (t < kL) {
    float v = nb[t];
    int rank = 0;
    for (int j = 0; j < kL; ++j) {
      float u = nb[j];
      rank += (u < v || (u == v && j < t)) ? 1 : 0;
    }
    if (rank < kKeep) ids_keep[b * kKeep + rank] = t;
    idsr_out[b * kL + t] = (float)rank;
    mask_out[b * kL + t] = (rank < kKeep) ? 0.f : 1.f;
  }
}

// ---------------- gather kept tokens (+ pos embed) ----------------
__global__ __launch_bounds__(256) void gather_kernel(const float* __restrict__ x0,
                                                     const int* __restrict__ ids_keep,
                                                     const float* __restrict__ pos,
                                                     float* __restrict__ hs) {
  int m = blockIdx.x;
  int b = m / kKeep, k = m % kKeep;
  int l = ids_keep[b * kKeep + k];
  const float* src = x0 + (size_t)(b * kL + l) * kD;
  const float* pp  = pos + (size_t)l * kD;
  float* dst = hs + (size_t)m * kD;
  for (int d = threadIdx.x; d < kD; d += 256) dst[d] = src[d] + pp[d];
}

// ---------------- res += hs ; out = LN(res)*w + b ----------------
template <int DD>
__global__ __launch_bounds__(256) void add_ln_kernel(const float* __restrict__ hs,
                                                     float* __restrict__ res,
                                                     const float* __restrict__ w,
                                                     const float* __restrict__ b,
                                                     float* __restrict__ out) {
  constexpr int PT = DD / 256;
  __shared__ float sbuf[4];
  int m = blockIdx.x;
  int t = threadIdx.x;
  float v[PT];
  float s = 0.f;
#pragma unroll
  for (int i = 0; i < PT; ++i) {
    int d = t + i * 256;
    v[i] = res[(size_t)m * DD + d] + hs[(size_t)m * DD + d];
    s += v[i];
  }
  float mean = block_sum256(s, sbuf) * (1.f / DD);
  float s2 = 0.f;
#pragma unroll
  for (int i = 0; i < PT; ++i) { float d0 = v[i] - mean; s2 += d0 * d0; }
  float var = block_sum256(s2, sbuf) * (1.f / DD);
  float rstd = rsqrtf(var + kEps);
#pragma unroll
  for (int i = 0; i < PT; ++i) {
    int d = t + i * 256;
    res[(size_t)m * DD + d] = v[i];
    out[(size_t)m * DD + d] = (v[i] - mean) * rstd * w[d] + b[d];
  }
}

// ---------------- depthwise causal conv (k=4) + SiLU ----------------
__global__ __launch_bounds__(256) void conv_silu_kernel(const float* __restrict__ xz,
                                                        const float* __restrict__ cw,
                                                        const float* __restrict__ cb,
                                                        float* __restrict__ xc) {
  int idx = blockIdx.x * 256 + threadIdx.x;
  if (idx >= kTok * kDI) return;
  int d  = idx % kDI;
  int mt = idx / kDI;
  int t = mt % kKeep;
  int b = mt / kKeep;
  float acc = cb[d];
#pragma unroll
  for (int k = 0; k < 4; ++k) {
    int tt = t - 3 + k;
    if (tt >= 0) acc += xz[(size_t)(b * kKeep + tt) * 3072 + d] * cw[d * 4 + k];
  }
  xc[idx] = acc / (1.f + expf(-acc));
}

// ---------------- selective scan (64-thread blocks, B/C in LDS) ----------------
__global__ __launch_bounds__(64) void scan_kernel(const float* __restrict__ dt,
                                                  const float* __restrict__ xc,
                                                  const float* __restrict__ xdbl,
                                                  const float* __restrict__ A_log,
                                                  const float* __restrict__ D_skip,
                                                  float* __restrict__ y) {
  __shared__ float bcs[kKeep][32];
  int d = blockIdx.x * 64 + threadIdx.x;  // grid.x = 24
  int b = blockIdx.y;
  for (int i = threadIdx.x; i < kKeep * 32; i += 64) {
    int t = i >> 5, n = i & 31;
    bcs[t][n] = xdbl[(size_t)(b * kKeep + t) * 80 + kDTR + n];
  }
  __syncthreads();
  float Aloc[kN];
#pragma unroll
  for (int n = 0; n < kN; ++n) Aloc[n] = -expf(A_log[d * kN + n]);
  float dsk = D_skip[d];
  float s[kN];
#pragma unroll
  for (int n = 0; n < kN; ++n) s[n] = 0.f;

  size_t base = (size_t)(b * kKeep) * kDI + d;
  float dtv = dt[base];
  float xcv = xc[base];
  for (int t = 0; t < kKeep; ++t) {
    float dtn = 0.f, xcn = 0.f;
    if (t + 1 < kKeep) {                 // prefetch next step
      dtn = dt[base + (size_t)(t + 1) * kDI];
      xcn = xc[base + (size_t)(t + 1) * kDI];
    }
    float dx = dtv * xcv;
    float yv = 0.f;
#pragma unroll
    for (int n = 0; n < kN; ++n) {
      float sn = expf(dtv * Aloc[n]) * s[n] + dx * bcs[t][n];
      s[n] = sn;
      yv += sn * bcs[t][16 + n];
    }
    y[base + (size_t)t * kDI] = yv + dsk * xcv;
    dtv = dtn; xcv = xcn;
  }
}

// ---------------- y2 = (LN(y)*w+b) * silu(z) ----------------
__global__ __launch_bounds__(256) void ssm_ln_silu_kernel(const float* __restrict__ y,
                                                          const float* __restrict__ xz,
                                                          const float* __restrict__ w,
                                                          const float* __restrict__ b,
                                                          float* __restrict__ y2) {
  constexpr int PT = kDI / 256;  // 6
  __shared__ float sbuf[4];
  int m = blockIdx.x;
  int t = threadIdx.x;
  float v[PT];
  float s = 0.f;
#pragma unroll
  for (int i = 0; i < PT; ++i) {
    int d = t + i * 256;
    v[i] = y[(size_t)m * kDI + d];
    s += v[i];
  }
  float mean = block_sum256(s, sbuf) * (1.f / kDI);
  float s2 = 0.f;
#pragma unroll
  for (int i = 0; i < PT; ++i) { float d0 = v[i] - mean; s2 += d0 * d0; }
  float var = block_sum256(s2, sbuf) * (1.f / kDI);
  float rstd = rsqrtf(var + kEps);
#pragma unroll
  for (int i = 0; i < PT; ++i) {
    int d = t + i * 256;
    float z = xz[(size_t)m * 3072 + kDI + d];
    y2[(size_t)m * kDI + d] =
        ((v[i] - mean) * rstd * w[d] + b[d]) * (z / (1.f + expf(-z)));
  }
}

}  // namespace

extern "C" void kernel_launch(void* const* d_in, const int* in_sizes, int n_in,
                              void* d_out, int out_size, void* d_ws, size_t ws_size,
                              hipStream_t stream) {
  const float* imgs       = (const float*)d_in[0];
  const float* noise      = (const float*)d_in[1];
  const float* patch_w    = (const float*)d_in[2];
  const float* patch_b    = (const float*)d_in[3];
  const float* pos_embed  = (const float*)d_in[4];
  const float* ln_w       = (const float*)d_in[5];
  const float* ln_b       = (const float*)d_in[6];
  const float* in_proj_w  = (const float*)d_in[7];
  const float* conv_w     = (const float*)d_in[8];
  const float* conv_b     = (const float*)d_in[9];
  const float* x_proj_w   = (const float*)d_in[10];
  const float* dt_w       = (const float*)d_in[11];
  const float* dt_b       = (const float*)d_in[12];
  const float* A_log      = (const float*)d_in[13];
  const float* D_skip     = (const float*)d_in[14];
  const float* ssm_ln_w   = (const float*)d_in[15];
  const float* ssm_ln_b   = (const float*)d_in[16];
  const float* out_proj_w = (const float*)d_in[17];
  const float* final_ln_w = (const float*)d_in[18];
  const float* final_ln_b = (const float*)d_in[19];

  float* out      = (float*)d_out;
  float* latent   = out;                       // 392*768
  float* mask_out = out + 301056;              // 8*196
  float* idsr_out = out + 301056 + 1568;       // 8*196

  // workspace layout (floats)
  float* ws   = (float*)d_ws;
  float* hs   = ws;                 // 301056
  float* res  = hs   + 301056;      // 301056
  float* h    = res  + 301056;      // 301056
  float* xz   = h    + 301056;      // 1204224 (392x3072)
  float* xc   = xz   + 1204224;     // 602112  (392x1536)
  float* xdbl = xc   + 602112;      // 31360   (392x80)
  float* dtb_ = xdbl + 31360;       // 602112  (392x1536)
  float* ybuf = dtb_ + 602112;      // 602112
  float* y2   = ybuf + 602112;      // 602112
  int*   ids_keep = (int*)(y2 + 602112);  // 392 ints
  // patch-stage aliases (disjoint in time with layer buffers)
  float* A2 = xz;  // 1568x768 fits in xz exactly
  float* x0 = xc;  // 1568x768 fits in xc+xdbl+dtb_

  // ---- patch embedding: im2col + split-K GEMM (bias = patch_b) ----
  {
    int tot = kPatchRows * kD;
    im2col_kernel<<<(tot + 255) / 256, 256, 0, stream>>>(imgs, A2);
    hipMemsetAsync(x0, 0, (size_t)kPatchRows * kD * sizeof(float), stream);
    gemm_bt<0, 4><<<dim3(25, 12, 4), 256, 0, stream>>>(A2, kD, patch_w, patch_b,
                                                       x0, kD, kPatchRows, kD, kD);
  }

  // ---- masking (argsort ranks) ----
  sort_kernel<<<kB, 256, 0, stream>>>(noise, ids_keep, mask_out, idsr_out);

  // ---- gather kept tokens + pos embed ----
  gather_kernel<<<kTok, 256, 0, stream>>>(x0, ids_keep, pos_embed, hs);

  // ---- res = 0 ----
  hipMemsetAsync(res, 0, (size_t)kTok * kD * sizeof(float), stream);

  // ---- 12 Mamba blocks ----
  for (int l = 0; l < 12; ++l) {
    const float* lnw  = ln_w  + (size_t)l * kD;
    const float* lnb  = ln_b  + (size_t)l * kD;
    const float* ipw  = in_proj_w  + (size_t)l * 2 * kDI * kD;
    const float* cw   = conv_w     + (size_t)l * kDI * 4;
    const float* cb   = conv_b     + (size_t)l * kDI;
    const float* xpw  = x_proj_w   + (size_t)l * (kDTR + 2 * kN) * kDI;
    const float* dtw  = dt_w       + (size_t)l * kDI * kDTR;
    const float* dtbv = dt_b       + (size_t)l * kDI;
    const float* alog = A_log      + (size_t)l * kDI * kN;
    const float* dsk  = D_skip     + (size_t)l * kDI;
    const float* slw  = ssm_ln_w   + (size_t)l * kDI;
    const float* slb  = ssm_ln_b   + (size_t)l * kDI;
    const float* opw  = out_proj_w + (size_t)l * kD * kDI;

    // res += hs ; h = LN(res)
    add_ln_kernel<kD><<<kTok, 256, 0, stream>>>(hs, res, lnw, lnb, h);

    // xz = h @ ipw^T   (392 x 3072, K=768), split-K x4 via atomics
    hipMemsetAsync(xz, 0, (size_t)kTok * 2 * kDI * sizeof(float), stream);
    gemm_bt<0, 4><<<dim3(7, 48, 4), 256, 0, stream>>>(h, kD, ipw, nullptr, xz,
                                                      2 * kDI, kTok, 2 * kDI, kD);

    // xc = silu(causal depthwise conv(xi) + cb)
    conv_silu_kernel<<<(kTok * kDI + 255) / 256, 256, 0, stream>>>(xz, cw, cb, xc);

    // xdbl = xc @ xpw^T  (392 x 80, K=1536), split-K x16 via atomics
    hipMemsetAsync(xdbl, 0, (size_t)kTok * 80 * sizeof(float), stream);
    gemm_bt<0, 16><<<dim3(7, 2, 16), 256, 0, stream>>>(xc, kDI, xpw, nullptr,
                                                       xdbl, 80, kTok, 80, kDI);

    // dt = softplus(dtr @ dtw^T + dt_b)  (392 x 1536, K=48)
    gemm_bt<1, 1><<<dim3(7, 24, 1), 256, 0, stream>>>(xdbl, 80, dtw, dtbv, dtb_,
                                                      kDI, kTok, kDI, kDTR);

    // selective scan -> ybuf (+ D skip)
    scan_kernel<<<dim3(24, kB), 64, 0, stream>>>(dtb_, xc, xdbl, alog, dsk, ybuf);

    // y2 = LN(ybuf)*slw+slb * silu(z)
    ssm_ln_silu_kernel<<<kTok, 256, 0, stream>>>(ybuf, xz, slw, slb, y2);

    // hs = y2 @ opw^T  (392 x 768, K=1536), split-K x8 via atomics
    hipMemsetAsync(hs, 0, (size_t)kTok * kD * sizeof(float), stream);
    gemm_bt<0, 8><<<dim3(7, 12, 8), 256, 0, stream>>>(y2, kDI, opw, nullptr, hs,
                                                      kD, kTok, kD, kDI);
  }

  // ---- latent = LN(res + hs) ----
  add_ln_kernel<kD><<<kTok, 256, 0, stream>>>(hs, res, final_ln_w, final_ln_b,
                                              latent);
}

// Round 9
// 1600.203 us; speedup vs baseline: 5.1898x; 1.6616x over previous
//
#include <hip/hip_runtime.h>
#include <cstdint>
#include <cstddef>

namespace {

constexpr int kD    = 768;
constexpr int kDI   = 1536;
constexpr int kN    = 16;
constexpr int kDTR  = 48;
constexpr int kL    = 196;
constexpr int kKeep = 49;
constexpr int kB    = 8;
constexpr int kTok  = kB * kKeep;   // 392
constexpr int kPatchRows = kB * kL; // 1568
constexpr float kEps = 1e-5f;

typedef __attribute__((ext_vector_type(8))) short short8;
typedef __attribute__((ext_vector_type(4))) float f32x4;

// f32 -> bf16 round-to-nearest-even
__device__ __forceinline__ short f2bf(float f) {
  unsigned u = __float_as_uint(f);
  return (short)((u + 0x7FFFu + ((u >> 16) & 1u)) >> 16);
}

__device__ __forceinline__ short8 pack8(float4 a, float4 b) {
  short8 r;
  r[0] = f2bf(a.x); r[1] = f2bf(a.y); r[2] = f2bf(a.z); r[3] = f2bf(a.w);
  r[4] = f2bf(b.x); r[5] = f2bf(b.y); r[6] = f2bf(b.z); r[7] = f2bf(b.w);
  return r;
}

// ---------------- block reduction (256 threads = 4 waves) ----------------
__device__ __forceinline__ float block_sum256(float x, float* sbuf) {
#pragma unroll
  for (int o = 32; o > 0; o >>= 1) x += __shfl_down(x, o, 64);
  int wid = threadIdx.x >> 6;
  if ((threadIdx.x & 63) == 0) sbuf[wid] = x;
  __syncthreads();
  float r = sbuf[0] + sbuf[1] + sbuf[2] + sbuf[3];
  __syncthreads();
  return r;
}

// ---------------- im2col for patch embedding ----------------
__global__ __launch_bounds__(256) void im2col_kernel(const float* __restrict__ imgs,
                                                     float* __restrict__ A2) {
  int idx = blockIdx.x * 256 + threadIdx.x;
  if (idx >= kPatchRows * kD) return;
  int col = idx % kD;
  int row = idx / kD;
  int b = row / kL, l = row % kL;
  int gy = l / 14, gx = l % 14;
  int c   = col >> 8;
  int rem = col & 255;
  int py = rem >> 4, px = rem & 15;
  A2[idx] = imgs[((b * 3 + c) * 224 + gy * 16 + py) * 224 + gx * 16 + px];
}

// ---------------- bf16 MFMA GEMM: C[M,N] = act(A[M,lda] @ W[N,K]^T + bias) ----
// 64x64 tile, BK=64, 256 threads = 4 waves (2x2), each wave 32x32 via 2x2
// mfma_f32_16x16x32_bf16. f32 global loads, RNE-converted to bf16 in LDS
// (k-subtiled [8][64][8] layout -> conflict-free ds_read_b128 fragments).
// SPLIT==1: direct store, optional bias / ACT(1=softplus).
// SPLIT>1 : blockIdx.z selects K-chunk; partials to C + z*M*N (dense, no
//           atomics) -> reduce_kernel sums them. bias/ACT must be 0.
// KG: K-guard for K not a multiple of 64 (zero-pad); needs K%4==0.
template <int SPLIT, int ACT, bool KG>
__global__ __launch_bounds__(256) void gemm_mfma(const float* __restrict__ A, int lda,
                                                 const float* __restrict__ W,
                                                 const float* __restrict__ bias,
                                                 float* __restrict__ C, int ldc,
                                                 int M, int N, int K) {
  __shared__ __align__(16) short As[8][64][8];
  __shared__ __align__(16) short Bs[8][64][8];
  const int tid = threadIdx.x;
  const int bm = blockIdx.x * 64;
  const int bn = blockIdx.y * 64;
  const int kc = K / SPLIT;
  const int k0 = blockIdx.z * kc;
  const int nk = (kc + 63) / 64;
  const int sr = tid >> 2;       // staged row 0..63
  const int sq = tid & 3;        // 16-wide k chunk
  const int lane = tid & 63;
  const int wm = ((tid >> 6) >> 1) * 32;  // wave m-offset
  const int wn = ((tid >> 6) & 1) * 32;   // wave n-offset
  const bool mok = (bm + sr) < M;
  const bool nok = (bn + sr) < N;
  const float* Ap = A + (size_t)(bm + sr) * lda + k0 + sq * 16;
  const float* Wp = W + (size_t)(bn + sr) * K + k0 + sq * 16;

  f32x4 acc[2][2];
#pragma unroll
  for (int i = 0; i < 2; ++i)
#pragma unroll
    for (int j = 0; j < 2; ++j) acc[i][j] = (f32x4){0.f, 0.f, 0.f, 0.f};

  for (int kt = 0; kt < nk; ++kt) {
    const int kb = kt * 64;
    const float4 z4 = make_float4(0.f, 0.f, 0.f, 0.f);
    float4 a0 = z4, a1 = z4, a2 = z4, a3 = z4;
    float4 w0 = z4, w1 = z4, w2 = z4, w3 = z4;
    const float* ap = Ap + kb;
    const float* wp = Wp + kb;
    if (!KG) {
      if (mok) {
        a0 = *(const float4*)ap;       a1 = *(const float4*)(ap + 4);
        a2 = *(const float4*)(ap + 8); a3 = *(const float4*)(ap + 12);
      }
      if (nok) {
        w0 = *(const float4*)wp;       w1 = *(const float4*)(wp + 4);
        w2 = *(const float4*)(wp + 8); w3 = *(const float4*)(wp + 12);
      }
    } else {
      const int kq = k0 + kb + sq * 16;  // absolute k of this thread's chunk
      if (mok) {
        if (kq + 4  <= K) a0 = *(const float4*)ap;
        if (kq + 8  <= K) a1 = *(const float4*)(ap + 4);
        if (kq + 12 <= K) a2 = *(const float4*)(ap + 8);
        if (kq + 16 <= K) a3 = *(const float4*)(ap + 12);
      }
      if (nok) {
        if (kq + 4  <= K) w0 = *(const float4*)wp;
        if (kq + 8  <= K) w1 = *(const float4*)(wp + 4);
        if (kq + 12 <= K) w2 = *(const float4*)(wp + 8);
        if (kq + 16 <= K) w3 = *(const float4*)(wp + 12);
      }
    }
    if (kt) __syncthreads();
    *(short8*)&As[sq * 2][sr][0]     = pack8(a0, a1);
    *(short8*)&As[sq * 2 + 1][sr][0] = pack8(a2, a3);
    *(short8*)&Bs[sq * 2][sr][0]     = pack8(w0, w1);
    *(short8*)&Bs[sq * 2 + 1][sr][0] = pack8(w2, w3);
    __syncthreads();
#pragma unroll
    for (int kh = 0; kh < 2; ++kh) {
      const int kg = kh * 4 + (lane >> 4);
      short8 af0 = *(const short8*)&As[kg][wm + (lane & 15)][0];
      short8 af1 = *(const short8*)&As[kg][wm + 16 + (lane & 15)][0];
      short8 bf0 = *(const short8*)&Bs[kg][wn + (lane & 15)][0];
      short8 bf1 = *(const short8*)&Bs[kg][wn + 16 + (lane & 15)][0];
      acc[0][0] = __builtin_amdgcn_mfma_f32_16x16x32_bf16(af0, bf0, acc[0][0], 0, 0, 0);
      acc[0][1] = __builtin_amdgcn_mfma_f32_16x16x32_bf16(af0, bf1, acc[0][1], 0, 0, 0);
      acc[1][0] = __builtin_amdgcn_mfma_f32_16x16x32_bf16(af1, bf0, acc[1][0], 0, 0, 0);
      acc[1][1] = __builtin_amdgcn_mfma_f32_16x16x32_bf16(af1, bf1, acc[1][1], 0, 0, 0);
    }
  }

  // store: m = (lane>>4)*4 + reg (first-operand free dim), n = lane&15
  const int mrow = (lane >> 4) * 4;
  const int ncol = lane & 15;
#pragma unroll
  for (int i2 = 0; i2 < 2; ++i2)
#pragma unroll
    for (int j2 = 0; j2 < 2; ++j2) {
      int n = bn + wn + j2 * 16 + ncol;
      if (n >= N) continue;
      float bv = 0.f;
      if (SPLIT == 1) bv = bias ? bias[n] : 0.f;
#pragma unroll
      for (int r = 0; r < 4; ++r) {
        int m = bm + wm + i2 * 16 + mrow + r;
        if (m >= M) continue;
        float v = acc[i2][j2][r];
        if (SPLIT == 1) {
          v += bv;
          if (ACT == 1) v = (v > 20.f) ? v : log1pf(expf(v));
          C[(size_t)m * ldc + n] = v;
        } else {
          C[(size_t)blockIdx.z * ((size_t)M * N) + (size_t)m * N + n] = v;
        }
      }
    }
}

// ---------------- sum split-K partials: out = sum_z part[z] ----------------
__global__ __launch_bounds__(256) void reduce_kernel(const float* __restrict__ part,
                                                     float* __restrict__ out,
                                                     int total4, int Z) {
  int i = blockIdx.x * 256 + threadIdx.x;
  if (i >= total4) return;
  const float4* p = (const float4*)part;
  float4 s = p[i];
  for (int z = 1; z < Z; ++z) {
    float4 v = p[(size_t)z * total4 + i];
    s.x += v.x; s.y += v.y; s.z += v.z; s.w += v.w;
  }
  ((float4*)out)[i] = s;
}

// ---------------- argsort / mask ----------------
__global__ __launch_bounds__(256) void sort_kernel(const float* __restrict__ noise,
                                                   int* __restrict__ ids_keep,
                                                   float* __restrict__ mask_out,
                                                   float* __restrict__ idsr_out) {
  __shared__ float nb[kL];
  int b = blockIdx.x;
  int t = threadIdx.x;
  if (t < kL) nb[t] = noise[b * kL + t];
  __syncthreads();
  if (t < kL) {
    float v = nb[t];
    int rank = 0;
    for (int j = 0; j < kL; ++j) {
      float u = nb[j];
      rank += (u < v || (u == v && j < t)) ? 1 : 0;
    }
    if (rank < kKeep) ids_keep[b * kKeep + rank] = t;
    idsr_out[b * kL + t] = (float)rank;
    mask_out[b * kL + t] = (rank < kKeep) ? 0.f : 1.f;
  }
}

// ---------------- gather kept tokens (+ pos embed) ----------------
__global__ __launch_bounds__(256) void gather_kernel(const float* __restrict__ x0,
                                                     const int* __restrict__ ids_keep,
                                                     const float* __restrict__ pos,
                                                     float* __restrict__ hs) {
  int m = blockIdx.x;
  int b = m / kKeep, k = m % kKeep;
  int l = ids_keep[b * kKeep + k];
  const float* src = x0 + (size_t)(b * kL + l) * kD;
  const float* pp  = pos + (size_t)l * kD;
  float* dst = hs + (size_t)m * kD;
  for (int d = threadIdx.x; d < kD; d += 256) dst[d] = src[d] + pp[d];
}

// ---------------- res += hs ; out = LN(res)*w + b ----------------
template <int DD>
__global__ __launch_bounds__(256) void add_ln_kernel(const float* __restrict__ hs,
                                                     float* __restrict__ res,
                                                     const float* __restrict__ w,
                                                     const float* __restrict__ b,
                                                     float* __restrict__ out) {
  constexpr int PT = DD / 256;
  __shared__ float sbuf[4];
  int m = blockIdx.x;
  int t = threadIdx.x;
  float v[PT];
  float s = 0.f;
#pragma unroll
  for (int i = 0; i < PT; ++i) {
    int d = t + i * 256;
    v[i] = res[(size_t)m * DD + d] + hs[(size_t)m * DD + d];
    s += v[i];
  }
  float mean = block_sum256(s, sbuf) * (1.f / DD);
  float s2 = 0.f;
#pragma unroll
  for (int i = 0; i < PT; ++i) { float d0 = v[i] - mean; s2 += d0 * d0; }
  float var = block_sum256(s2, sbuf) * (1.f / DD);
  float rstd = rsqrtf(var + kEps);
#pragma unroll
  for (int i = 0; i < PT; ++i) {
    int d = t + i * 256;
    res[(size_t)m * DD + d] = v[i];
    out[(size_t)m * DD + d] = (v[i] - mean) * rstd * w[d] + b[d];
  }
}

// ---------------- depthwise causal conv (k=4) + SiLU ----------------
__global__ __launch_bounds__(256) void conv_silu_kernel(const float* __restrict__ xz,
                                                        const float* __restrict__ cw,
                                                        const float* __restrict__ cb,
                                                        float* __restrict__ xc) {
  int idx = blockIdx.x * 256 + threadIdx.x;
  if (idx >= kTok * kDI) return;
  int d  = idx % kDI;
  int mt = idx / kDI;
  int t = mt % kKeep;
  int b = mt / kKeep;
  float acc = cb[d];
#pragma unroll
  for (int k = 0; k < 4; ++k) {
    int tt = t - 3 + k;
    if (tt >= 0) acc += xz[(size_t)(b * kKeep + tt) * 3072 + d] * cw[d * 4 + k];
  }
  xc[idx] = acc / (1.f + expf(-acc));
}

// ---------------- selective scan (64-thread blocks, B/C in LDS) ----------------
__global__ __launch_bounds__(64) void scan_kernel(const float* __restrict__ dt,
                                                  const float* __restrict__ xc,
                                                  const float* __restrict__ xdbl,
                                                  const float* __restrict__ A_log,
                                                  const float* __restrict__ D_skip,
                                                  float* __restrict__ y) {
  __shared__ float bcs[kKeep][32];
  int d = blockIdx.x * 64 + threadIdx.x;  // grid.x = 24
  int b = blockIdx.y;
  for (int i = threadIdx.x; i < kKeep * 32; i += 64) {
    int t = i >> 5, n = i & 31;
    bcs[t][n] = xdbl[(size_t)(b * kKeep + t) * 80 + kDTR + n];
  }
  __syncthreads();
  float Aloc[kN];
#pragma unroll
  for (int n = 0; n < kN; ++n) Aloc[n] = -expf(A_log[d * kN + n]);
  float dsk = D_skip[d];
  float s[kN];
#pragma unroll
  for (int n = 0; n < kN; ++n) s[n] = 0.f;

  size_t base = (size_t)(b * kKeep) * kDI + d;
  float dtv = dt[base];
  float xcv = xc[base];
  for (int t = 0; t < kKeep; ++t) {
    float dtn = 0.f, xcn = 0.f;
    if (t + 1 < kKeep) {                 // prefetch next step
      dtn = dt[base + (size_t)(t + 1) * kDI];
      xcn = xc[base + (size_t)(t + 1) * kDI];
    }
    float dx = dtv * xcv;
    float yv = 0.f;
#pragma unroll
    for (int n = 0; n < kN; ++n) {
      float sn = expf(dtv * Aloc[n]) * s[n] + dx * bcs[t][n];
      s[n] = sn;
      yv += sn * bcs[t][16 + n];
    }
    y[base + (size_t)t * kDI] = yv + dsk * xcv;
    dtv = dtn; xcv = xcn;
  }
}

// ---------------- y2 = (LN(y)*w+b) * silu(z) ----------------
__global__ __launch_bounds__(256) void ssm_ln_silu_kernel(const float* __restrict__ y,
                                                          const float* __restrict__ xz,
                                                          const float* __restrict__ w,
                                                          const float* __restrict__ b,
                                                          float* __restrict__ y2) {
  constexpr int PT = kDI / 256;  // 6
  __shared__ float sbuf[4];
  int m = blockIdx.x;
  int t = threadIdx.x;
  float v[PT];
  float s = 0.f;
#pragma unroll
  for (int i = 0; i < PT; ++i) {
    int d = t + i * 256;
    v[i] = y[(size_t)m * kDI + d];
    s += v[i];
  }
  float mean = block_sum256(s, sbuf) * (1.f / kDI);
  float s2 = 0.f;
#pragma unroll
  for (int i = 0; i < PT; ++i) { float d0 = v[i] - mean; s2 += d0 * d0; }
  float var = block_sum256(s2, sbuf) * (1.f / kDI);
  float rstd = rsqrtf(var + kEps);
#pragma unroll
  for (int i = 0; i < PT; ++i) {
    int d = t + i * 256;
    float z = xz[(size_t)m * 3072 + kDI + d];
    y2[(size_t)m * kDI + d] =
        ((v[i] - mean) * rstd * w[d] + b[d]) * (z / (1.f + expf(-z)));
  }
}

}  // namespace

extern "C" void kernel_launch(void* const* d_in, const int* in_sizes, int n_in,
                              void* d_out, int out_size, void* d_ws, size_t ws_size,
                              hipStream_t stream) {
  const float* imgs       = (const float*)d_in[0];
  const float* noise      = (const float*)d_in[1];
  const float* patch_w    = (const float*)d_in[2];
  const float* patch_b    = (const float*)d_in[3];
  const float* pos_embed  = (const float*)d_in[4];
  const float* ln_w       = (const float*)d_in[5];
  const float* ln_b       = (const float*)d_in[6];
  const float* in_proj_w  = (const float*)d_in[7];
  const float* conv_w     = (const float*)d_in[8];
  const float* conv_b     = (const float*)d_in[9];
  const float* x_proj_w   = (const float*)d_in[10];
  const float* dt_w       = (const float*)d_in[11];
  const float* dt_b       = (const float*)d_in[12];
  const float* A_log      = (const float*)d_in[13];
  const float* D_skip     = (const float*)d_in[14];
  const float* ssm_ln_w   = (const float*)d_in[15];
  const float* ssm_ln_b   = (const float*)d_in[16];
  const float* out_proj_w = (const float*)d_in[17];
  const float* final_ln_w = (const float*)d_in[18];
  const float* final_ln_b = (const float*)d_in[19];

  float* out      = (float*)d_out;
  float* latent   = out;                       // 392*768
  float* mask_out = out + 301056;              // 8*196
  float* idsr_out = out + 301056 + 1568;       // 8*196

  // workspace layout (floats)
  float* ws   = (float*)d_ws;
  float* hs   = ws;                 // 301056
  float* res  = hs   + 301056;      // 301056
  float* h    = res  + 301056;      // 301056
  float* xz   = h    + 301056;      // 1204224 (392x3072)
  float* xc   = xz   + 1204224;     // 602112  (392x1536)
  float* xdbl = xc   + 602112;      // 31360   (392x80)
  float* dtb_ = xdbl + 31360;       // 602112  (392x1536)
  float* ybuf = dtb_ + 602112;      // 602112
  float* y2   = ybuf + 602112;      // 602112
  int*   ids_keep = (int*)(y2 + 602112);  // 392 ints
  // patch-stage aliases (disjoint in time with layer buffers)
  float* A2 = xz;  // 1568x768 fits in xz exactly
  float* x0 = xc;  // 1568x768 fits in xc+xdbl+dtb_
  // split-K partial overlays (dead regions at their use time):
  //   xdbl partials: 24 x 31360 = 752640 f  -> ybuf..y2 (scan/ssm write later)
  //   out_proj partials: 4 x 301056 = 1204224 f -> dtb_..ybuf (both consumed)
  float* part_xdbl = ybuf;
  float* part_out  = dtb_;

  // ---- patch embedding: im2col + MFMA GEMM (bias = patch_b) ----
  {
    int tot = kPatchRows * kD;
    im2col_kernel<<<(tot + 255) / 256, 256, 0, stream>>>(imgs, A2);
    gemm_mfma<1, 0, false><<<dim3(25, 12, 1), 256, 0, stream>>>(
        A2, kD, patch_w, patch_b, x0, kD, kPatchRows, kD, kD);
  }

  // ---- masking (argsort ranks) ----
  sort_kernel<<<kB, 256, 0, stream>>>(noise, ids_keep, mask_out, idsr_out);

  // ---- gather kept tokens + pos embed ----
  gather_kernel<<<kTok, 256, 0, stream>>>(x0, ids_keep, pos_embed, hs);

  // ---- res = 0 ----
  hipMemsetAsync(res, 0, (size_t)kTok * kD * sizeof(float), stream);

  // ---- 12 Mamba blocks ----
  for (int l = 0; l < 12; ++l) {
    const float* lnw  = ln_w  + (size_t)l * kD;
    const float* lnb  = ln_b  + (size_t)l * kD;
    const float* ipw  = in_proj_w  + (size_t)l * 2 * kDI * kD;
    const float* cw   = conv_w     + (size_t)l * kDI * 4;
    const float* cb   = conv_b     + (size_t)l * kDI;
    const float* xpw  = x_proj_w   + (size_t)l * (kDTR + 2 * kN) * kDI;
    const float* dtw  = dt_w       + (size_t)l * kDI * kDTR;
    const float* dtbv = dt_b       + (size_t)l * kDI;
    const float* alog = A_log      + (size_t)l * kDI * kN;
    const float* dsk  = D_skip     + (size_t)l * kDI;
    const float* slw  = ssm_ln_w   + (size_t)l * kDI;
    const float* slb  = ssm_ln_b   + (size_t)l * kDI;
    const float* opw  = out_proj_w + (size_t)l * kD * kDI;

    // res += hs ; h = LN(res)
    add_ln_kernel<kD><<<kTok, 256, 0, stream>>>(hs, res, lnw, lnb, h);

    // xz = h @ ipw^T   (392 x 3072, K=768)
    gemm_mfma<1, 0, false><<<dim3(7, 48, 1), 256, 0, stream>>>(
        h, kD, ipw, nullptr, xz, 2 * kDI, kTok, 2 * kDI, kD);

    // xc = silu(causal depthwise conv(xi) + cb)
    conv_silu_kernel<<<(kTok * kDI + 255) / 256, 256, 0, stream>>>(xz, cw, cb, xc);

    // xdbl = xc @ xpw^T  (392 x 80, K=1536), split-K x24 -> partials + reduce
    gemm_mfma<24, 0, false><<<dim3(7, 2, 24), 256, 0, stream>>>(
        xc, kDI, xpw, nullptr, part_xdbl, 80, kTok, 80, kDI);
    reduce_kernel<<<(7840 + 255) / 256, 256, 0, stream>>>(part_xdbl, xdbl, 7840, 24);

    // dt = softplus(dtr @ dtw^T + dt_b)  (392 x 1536, K=48, zero-padded to 64)
    gemm_mfma<1, 1, true><<<dim3(7, 24, 1), 256, 0, stream>>>(
        xdbl, 80, dtw, dtbv, dtb_, kDI, kTok, kDI, kDTR);

    // selective scan -> ybuf (+ D skip)
    scan_kernel<<<dim3(24, kB), 64, 0, stream>>>(dtb_, xc, xdbl, alog, dsk, ybuf);

    // y2 = LN(ybuf)*slw+slb * silu(z)
    ssm_ln_silu_kernel<<<kTok, 256, 0, stream>>>(ybuf, xz, slw, slb, y2);

    // hs = y2 @ opw^T  (392 x 768, K=1536), split-K x4 -> partials + reduce
    gemm_mfma<4, 0, false><<<dim3(7, 12, 4), 256, 0, stream>>>(
        y2, kDI, opw, nullptr, part_out, kD, kTok, kD, kDI);
    reduce_kernel<<<(75264 + 255) / 256, 256, 0, stream>>>(part_out, hs, 75264, 4);
  }

  // ---- latent = LN(res + hs) ----
  add_ln_kernel<kD><<<kTok, 256, 0, stream>>>(hs, res, final_ln_w, final_ln_b,
                                              latent);
}